// Round 10
// baseline (229.554 us; speedup 1.0000x reference)
//
#include <hip/hip_runtime.h>

typedef short short8 __attribute__((ext_vector_type(8)));
typedef float f32x4 __attribute__((ext_vector_type(4)));

// ---------------- bf16 helpers ----------------

__device__ inline unsigned short f2bf(float f) {
    union { float f; unsigned u; } v; v.f = f;
    unsigned r = v.u + 0x7fffu + ((v.u >> 16) & 1u);
    return (unsigned short)(r >> 16);
}
__device__ inline unsigned pack2(float a, float b) {
    return (unsigned)f2bf(a) | ((unsigned)f2bf(b) << 16);
}
__device__ inline float bflo(unsigned u) { union { unsigned q; float f; } c; c.q = u << 16; return c.f; }
__device__ inline float bfhi(unsigned u) { union { unsigned q; float f; } c; c.q = u & 0xffff0000u; return c.f; }

#define ACC8(vv)                                     \
    acc[0] += bflo(vv.x); acc[1] += bfhi(vv.x);      \
    acc[2] += bflo(vv.y); acc[3] += bfhi(vv.y);      \
    acc[4] += bflo(vv.z); acc[5] += bfhi(vv.z);      \
    acc[6] += bflo(vv.w); acc[7] += bfhi(vv.w);

// Per-node edge-vectorized gather: EW edges in flight per load inst (lane e_off = which
// edge, chunk = which 16B piece of the row). TPN = uint4 chunks per row. All lanes of a
// wave work the SAME node -> no degree divergence. Strided per-lane loop [beg+eo, end) step EW.
template <int TPN, int EW, typename F>
__device__ __forceinline__ void node_gather(float acc[8], const uint4* __restrict__ x,
                                            int chunk, int eo, int beg, int end, F geti) {
    int k = beg + eo;
    // 4-deep unroll: 4*EW edges, 4 loads in flight
    for (; k + 3 * EW < end; k += 4 * EW) {
        int i0 = geti(k), i1 = geti(k + EW), i2 = geti(k + 2 * EW), i3 = geti(k + 3 * EW);
        uint4 v0 = x[(size_t)i0 * TPN + chunk];
        uint4 v1 = x[(size_t)i1 * TPN + chunk];
        uint4 v2 = x[(size_t)i2 * TPN + chunk];
        uint4 v3 = x[(size_t)i3 * TPN + chunk];
        ACC8(v0) ACC8(v1) ACC8(v2) ACC8(v3)
    }
    for (; k < end; k += EW) {
        uint4 v = x[(size_t)geti(k) * TPN + chunk];
        ACC8(v)
    }
}

// ---------------- CSR build: direct-scatter bucket sort (R9, unchanged) ----------------

#define EPB 2048
#define NE 8
#define BSH 9
#define MAXBKT 128
#define DCAP 10240
#define BCAP 16384

__global__ __launch_bounds__(256) void megaA(
    const int* __restrict__ src, const int* __restrict__ dst,
    int* __restrict__ cursor, unsigned* __restrict__ pairs,
    int e, int nbkt, int nblk,
    const float4* __restrict__ feat, uint2* __restrict__ featb, int cvtb, int nf4,
    const float* __restrict__ W1, const float* __restrict__ Wh, const float* __restrict__ Wo,
    unsigned short* __restrict__ W1t, unsigned short* __restrict__ Wht,
    unsigned short* __restrict__ Wot) {
    __shared__ int hist[MAXBKT], loff[MAXBKT], cur[MAXBKT], gb[MAXBKT];
    __shared__ int sc[256];
    __shared__ unsigned sorted[EPB];
    int t = threadIdx.x, blk = blockIdx.x;
    if (blk < nblk) {
        for (int b = t; b < nbkt; b += 256) hist[b] = 0;
        __syncthreads();
        int base = blk * EPB;
        int cnt = min(EPB, e - base);
        unsigned packed[NE];
        int bb[NE];
#pragma unroll
        for (int j = 0; j < NE; j++) {
            int idx = base + t + 256 * j;
            bb[j] = -1;
            if (idx < e) {
                unsigned s0 = (unsigned)src[idx], d = (unsigned)dst[idx];
                int b = (int)(d >> BSH);
                bb[j] = b;
                packed[j] = s0 | ((d & ((1u << BSH) - 1)) << 16) | ((unsigned)b << 25);
                atomicAdd(&hist[b], 1);
            }
        }
        __syncthreads();
        int v = (t < nbkt) ? hist[t] : 0;
        sc[t] = v;
        __syncthreads();
        for (int off = 1; off < 256; off <<= 1) {
            int u = (t >= off) ? sc[t - off] : 0;
            __syncthreads();
            sc[t] += u;
            __syncthreads();
        }
        if (t < nbkt) {
            int ex = sc[t] - v;
            loff[t] = ex;
            cur[t] = ex;
            gb[t] = t * BCAP + (v ? atomicAdd(&cursor[t], v) : atomicAdd(&cursor[t], 0));
        }
        __syncthreads();
#pragma unroll
        for (int j = 0; j < NE; j++) {
            if (bb[j] >= 0) {
                int r = atomicAdd(&cur[bb[j]], 1);  // LDS only
                sorted[r] = packed[j];
            }
        }
        __syncthreads();
        for (int i = t; i < cnt; i += 256) {
            unsigned w = sorted[i];
            int b = (int)(w >> 25);
            pairs[gb[b] + (i - loff[b])] = w;
        }
    } else if (blk < nblk + cvtb) {
        int i = (blk - nblk) * 256 + t;
        if (i < nf4) {
            float4 v = feat[i];
            featb[i] = make_uint2(pack2(v.x, v.y), pack2(v.z, v.w));
        }
    } else {
        int i = (blk - nblk - cvtb) * 256 + t;
        if (i < 16384) {
            int k = i >> 7, nn = i & 127;
            W1t[nn * 128 + k] = f2bf(W1[i]);
        } else if (i < 32768) {
            int j = i - 16384, k = j >> 7, nn = j & 127;
            Wht[nn * 128 + k] = f2bf(Wh[j]);
        } else if (i < 40960) {
            int j = i - 32768, k = j >> 6, nn = j & 63;
            Wot[nn * 128 + k] = f2bf(Wo[j]);
        }
    }
}

__global__ __launch_bounds__(512) void buildD(const unsigned* __restrict__ pairs,
                                              const int* __restrict__ cursor,
                                              int* __restrict__ row_ptr, int* __restrict__ row_end,
                                              unsigned short* __restrict__ csr, int n) {
    __shared__ int hist[512], off[512];
    __shared__ unsigned short lcsr[DCAP];
    int t = threadIdx.x, b = blockIdx.x;
    int cnt = cursor[b], base = b * BCAP;
    hist[t] = 0;
    __syncthreads();
    for (int i = t; i < cnt; i += 512)
        atomicAdd(&hist[(pairs[base + i] >> 16) & 511], 1);
    __syncthreads();
    int v = hist[t];
    off[t] = v;
    __syncthreads();
    for (int o = 1; o < 512; o <<= 1) {
        int u = (t >= o) ? off[t - o] : 0;
        __syncthreads();
        off[t] += u;
        __syncthreads();
    }
    int excl = off[t] - v;
    int node = (b << BSH) + t;
    if (node < n) {
        row_ptr[node] = base + excl;
        row_end[node] = base + off[t];
    }
    __syncthreads();
    hist[t] = excl;
    __syncthreads();
    for (int i = t; i < cnt; i += 512) {
        unsigned w = pairs[base + i];
        int r = atomicAdd(&hist[(w >> 16) & 511], 1);  // LDS only
        if (r < DCAP) lcsr[r] = (unsigned short)(w & 0xFFFFu);
    }
    __syncthreads();
    int lim = min(cnt, DCAP);
    for (int i = t; i < lim; i += 512) csr[base + i] = lcsr[i];
}

// ---------------- Fused layer: edge-vectorized agg -> LDS -> MFMA GEMM [-> GEMM2] ----------------
// Block = 256 threads, 16 nodes. Wave w handles nodes w*4..w*4+3 SEQUENTIALLY; within a
// node all 64 lanes cooperate (4 edges x 16 chunks per load inst) -> no divergence.

#define ECAP 1024

template <bool SECOND>
__global__ __launch_bounds__(256) void fused_layer(
    const uint4* __restrict__ x, const int* __restrict__ row_ptr,
    const int* __restrict__ row_end, const unsigned short* __restrict__ csr,
    const short8* __restrict__ Bt, const float* __restrict__ bias,
    unsigned short* __restrict__ out_h,   // !SECOND
    const short8* __restrict__ Bt2,       // SECOND
    unsigned short* __restrict__ out_y,   // SECOND
    int n) {
    __shared__ unsigned short As[16][136];
    __shared__ unsigned short Hs[SECOND ? 16 : 1][SECOND ? 136 : 1];
    __shared__ unsigned short eidx[ECAP];

    int t = threadIdx.x;
    int r0 = blockIdx.x * 16;
    int wid = t >> 6, lane = t & 63;
    int chunk = lane & 15, eo = lane >> 4;  // 4 edges in flight x 16 chunks

    int E0 = row_ptr[min(r0, n - 1)];
    int E1 = row_end[min(r0 + 15, n - 1)];
    int ecnt = min(E1 - E0, ECAP);
    bool staged = (E1 - E0) <= ECAP;
    for (int i = t; i < ecnt; i += 256) eidx[i] = csr[E0 + i];
    __syncthreads();

    // ---- Phase 1: per-node gather, 4 nodes per wave sequentially ----
#pragma unroll
    for (int nd = 0; nd < 4; nd++) {
        int nl = wid * 4 + nd;
        int node = r0 + nl;
        float acc[8] = {0.f, 0.f, 0.f, 0.f, 0.f, 0.f, 0.f, 0.f};
        if (node < n) {
            if (eo == 0) {  // self feature once (lanes 0-15)
                uint4 s0 = x[(size_t)node * 16 + chunk];
                ACC8(s0)
            }
            int beg = row_ptr[node], end = row_end[node];
            if (staged) {
                node_gather<16, 4>(acc, x, chunk, eo, beg - E0, end - E0,
                                   [&](int k) { return (int)eidx[k]; });
            } else {
                node_gather<16, 4>(acc, x, chunk, eo, beg, end,
                                   [&](int k) { return (int)csr[k]; });
            }
        }
        // reduce across the 4 edge groups (lanes xor 16, 32)
#pragma unroll
        for (int j = 0; j < 8; j++) {
            acc[j] += __shfl_xor(acc[j], 16, 64);
            acc[j] += __shfl_xor(acc[j], 32, 64);
        }
        if (eo == 0) {
            uint4 packed;
            packed.x = pack2(acc[0], acc[1]); packed.y = pack2(acc[2], acc[3]);
            packed.z = pack2(acc[4], acc[5]); packed.w = pack2(acc[6], acc[7]);
            ((uint4*)&As[nl][0])[chunk] = packed;
        }
    }
    __syncthreads();

    // ---- Phase 2: GEMM 16x128 @ 128x128 ----
    int lm = lane & 15, lq = lane >> 4;

    short8 a[4];
#pragma unroll
    for (int kc = 0; kc < 4; kc++)
        a[kc] = *(const short8*)&As[lm][kc * 32 + lq * 8];

    f32x4 hacc[2];
#pragma unroll
    for (int nt = 0; nt < 2; nt++) hacc[nt] = (f32x4){0.f, 0.f, 0.f, 0.f};
#pragma unroll
    for (int nt = 0; nt < 2; nt++) {
        const short8* Br = Bt + (size_t)((wid * 2 + nt) * 16 + lm) * 16;
#pragma unroll
        for (int kc = 0; kc < 4; kc++)
            hacc[nt] = __builtin_amdgcn_mfma_f32_16x16x32_bf16(a[kc], Br[kc * 4 + lq], hacc[nt], 0, 0, 0);
    }

    // ---- Epilogue ----
#pragma unroll
    for (int nt = 0; nt < 2; nt++) {
        int col = (wid * 2 + nt) * 16 + lm;
        float bv = bias[col];
#pragma unroll
        for (int i = 0; i < 4; i++) {
            int row = r0 + lq * 4 + i;
            float v = fmaxf(hacc[nt][i] + bv, 0.f);
            if (SECOND) {
                Hs[lq * 4 + i][col] = f2bf(v);
            } else if (row < n) {
                out_h[(size_t)row * 128 + col] = f2bf(v);
            }
        }
    }

    if (SECOND) {
        __syncthreads();
        short8 a2[4];
#pragma unroll
        for (int kc = 0; kc < 4; kc++)
            a2[kc] = *(const short8*)&Hs[lm][kc * 32 + lq * 8];
        f32x4 yacc = (f32x4){0.f, 0.f, 0.f, 0.f};
        const short8* Br2 = Bt2 + (size_t)(wid * 16 + lm) * 16;
#pragma unroll
        for (int kc = 0; kc < 4; kc++)
            yacc = __builtin_amdgcn_mfma_f32_16x16x32_bf16(a2[kc], Br2[kc * 4 + lq], yacc, 0, 0, 0);
        int col = wid * 16 + lm;
#pragma unroll
        for (int i = 0; i < 4; i++) {
            int row = r0 + lq * 4 + i;
            if (row < n) out_y[(size_t)row * 64 + col] = f2bf(yacc[i]);
        }
    }
}

// ---------------- Final aggregation (D=64) + bo + log_softmax ----------------
// 32 nodes/block; wave handles 8 nodes sequentially; 8 edges x 8 chunks per load inst.

#define ECAP2 1536

__global__ __launch_bounds__(256) void agg_lsm(
    const uint4* __restrict__ x, float* __restrict__ out,
    const int* __restrict__ row_ptr, const int* __restrict__ row_end,
    const unsigned short* __restrict__ csr, const float* __restrict__ bo, int n) {
    __shared__ unsigned short eidx[ECAP2];
    __shared__ float Zs[32][72];  // per-node z rows (+pad)
    int t = threadIdx.x;
    int r0 = blockIdx.x * 32;
    int wid = t >> 6, lane = t & 63;
    int chunk = lane & 7, eo = lane >> 3;  // 8 edges x 8 chunks

    int E0 = row_ptr[min(r0, n - 1)];
    int E1 = row_end[min(r0 + 31, n - 1)];
    int ecnt = min(E1 - E0, ECAP2);
    bool staged = (E1 - E0) <= ECAP2;
    for (int i = t; i < ecnt; i += 256) eidx[i] = csr[E0 + i];
    __syncthreads();

#pragma unroll
    for (int nd = 0; nd < 8; nd++) {
        int nl = wid * 8 + nd;
        int node = r0 + nl;
        float acc[8] = {0.f, 0.f, 0.f, 0.f, 0.f, 0.f, 0.f, 0.f};
        if (node < n) {
            if (eo == 0) {
                uint4 s0 = x[(size_t)node * 8 + chunk];
                ACC8(s0)
            }
            int beg = row_ptr[node], end = row_end[node];
            if (staged) {
                node_gather<8, 8>(acc, x, chunk, eo, beg - E0, end - E0,
                                  [&](int k) { return (int)eidx[k]; });
            } else {
                node_gather<8, 8>(acc, x, chunk, eo, beg, end,
                                  [&](int k) { return (int)csr[k]; });
            }
        }
#pragma unroll
        for (int j = 0; j < 8; j++) {
            acc[j] += __shfl_xor(acc[j], 8, 64);
            acc[j] += __shfl_xor(acc[j], 16, 64);
            acc[j] += __shfl_xor(acc[j], 32, 64);
        }
        if (eo == 0) {
#pragma unroll
            for (int j = 0; j < 8; j++) Zs[nl][chunk * 8 + j] = acc[j];
        }
    }
    __syncthreads();

    // log_softmax: 8 lanes per node (t>>3 = node-local, t&7 = chunk)
    int nl = t >> 3, col = t & 7;
    int node = r0 + nl;
    if (node >= n) return;
    float acc[8];
#pragma unroll
    for (int j = 0; j < 8; j++) acc[j] = Zs[nl][col * 8 + j];
    const float4* bo4 = (const float4*)bo;
    float4 bA = bo4[col * 2], bB = bo4[col * 2 + 1];
    acc[0] += bA.x; acc[1] += bA.y; acc[2] += bA.z; acc[3] += bA.w;
    acc[4] += bB.x; acc[5] += bB.y; acc[6] += bB.z; acc[7] += bB.w;
    float m = acc[0];
#pragma unroll
    for (int j = 1; j < 8; j++) m = fmaxf(m, acc[j]);
#pragma unroll
    for (int off = 1; off < 8; off <<= 1) m = fmaxf(m, __shfl_xor(m, off, 64));
    float s = 0.f;
#pragma unroll
    for (int j = 0; j < 8; j++) s += __expf(acc[j] - m);
#pragma unroll
    for (int off = 1; off < 8; off <<= 1) s += __shfl_xor(s, off, 64);
    float ls = m + __logf(s);
    float4 o0 = make_float4(acc[0] - ls, acc[1] - ls, acc[2] - ls, acc[3] - ls);
    float4 o1 = make_float4(acc[4] - ls, acc[5] - ls, acc[6] - ls, acc[7] - ls);
    float4* op = (float4*)(out + (size_t)node * 64 + col * 8);
    op[0] = o0;
    op[1] = o1;
}

// ---------------- launch ----------------

extern "C" void kernel_launch(void* const* d_in, const int* in_sizes, int n_in,
                              void* d_out, int out_size, void* d_ws, size_t ws_size,
                              hipStream_t stream) {
    const float* feature = (const float*)d_in[0];
    const int*   edges   = (const int*)d_in[1];
    const float* W1 = (const float*)d_in[2];
    const float* b1 = (const float*)d_in[3];
    const float* Wh = (const float*)d_in[4];
    const float* bh = (const float*)d_in[5];
    const float* Wo = (const float*)d_in[6];
    const float* bo = (const float*)d_in[7];

    int n = in_sizes[0] / 128;  // 50000 (< 65536 for 16-bit src packing)
    int e = in_sizes[1] / 2;    // 800000
    const int* src = edges;
    const int* dst = edges + e;

    int nbkt = (n + 511) >> BSH;       // 98
    int nblk = (e + EPB - 1) / EPB;    // 391
    int nf4 = n * 32;
    int cvtb = (nf4 + 255) / 256;

    char* ws = (char*)d_ws;
    auto take = [&](size_t bytes) {
        char* p = ws;
        ws += (bytes + 255) & ~(size_t)255;
        return p;
    };
    int* cursor  = (int*)take((size_t)nbkt * 4);
    int* row_ptr = (int*)take((size_t)n * 4);
    int* row_end = (int*)take((size_t)n * 4);
    unsigned* pairs = (unsigned*)take((size_t)nbkt * BCAP * 4);
    unsigned short* csr = (unsigned short*)take((size_t)nbkt * BCAP * 2);
    unsigned short* featb = (unsigned short*)take((size_t)n * 128 * 2);
    unsigned short* hb    = (unsigned short*)take((size_t)n * 128 * 2);
    unsigned short* yb    = (unsigned short*)take((size_t)n * 64 * 2);
    unsigned short* W1t = (unsigned short*)take(128 * 128 * 2);
    unsigned short* Wht = (unsigned short*)take(128 * 128 * 2);
    unsigned short* Wot = (unsigned short*)take(64 * 128 * 2);

    hipMemsetAsync(cursor, 0, (size_t)nbkt * 4, stream);
    megaA<<<nblk + cvtb + 160, 256, 0, stream>>>(
        src, dst, cursor, pairs, e, nbkt, nblk,
        (const float4*)feature, (uint2*)featb, cvtb, nf4,
        W1, Wh, Wo, W1t, Wht, Wot);
    buildD<<<nbkt, 512, 0, stream>>>(pairs, cursor, row_ptr, row_end, csr, n);

    int fblocks = (n + 15) / 16;

    // Layer 1: h1 = relu((x+agg(x))@W1+b1)
    fused_layer<false><<<fblocks, 256, 0, stream>>>(
        (const uint4*)featb, row_ptr, row_end, csr, (const short8*)W1t, b1,
        hb, nullptr, nullptr, n);

    // Layer 2 + layer-3 GEMM: h2 = relu((h1+agg(h1))@Wh+bh); y = h2@Wo
    fused_layer<true><<<fblocks, 256, 0, stream>>>(
        (const uint4*)hb, row_ptr, row_end, csr, (const short8*)Wht, bh,
        nullptr, (const short8*)Wot, yb, n);

    // out = log_softmax(y + agg(y) + bo)
    agg_lsm<<<(n + 31) / 32, 256, 0, stream>>>(
        (const uint4*)yb, (float*)d_out, row_ptr, row_end, csr, bo, n);
}